// Round 2
// baseline (352.360 us; speedup 1.0000x reference)
//
#include <hip/hip_runtime.h>
#include <math.h>

#define S 256
#define A 180
#define B 4
#define NSPLIT 8
#define ISTEPS (S / NSPLIT)  // 32

// Zero-init the output (harness poisons it with 0xAA; we accumulate atomically).
__global__ void radon_zero_kernel(float* __restrict__ out, int n) {
    int idx = blockIdx.x * 256 + threadIdx.x;
    if (idx < n) out[idx] = 0.0f;
}

// Apply inscribed-circle mask (dist <= S/2) into workspace.
// Integer test dx^2+dy^2 <= 128^2 is exactly equivalent to sqrt(...) <= 128.
__global__ void radon_mask_kernel(const float* __restrict__ in, float* __restrict__ out) {
    int idx = blockIdx.x * 256 + threadIdx.x;        // 0 .. B*S*S-1
    int p = idx & (S * S - 1);
    int y = p >> 8;
    int x = p & 255;
    int dx = x - 128, dy = y - 128;
    float v = in[idx];
    out[idx] = (dx * dx + dy * dy <= 16384) ? v : 0.0f;
}

// One block per (angle, i-chunk); thread j handles all 4 batches.
// px(i) = 127.5 + c*(i-127.5) - s*(j-127.5)
// py(i) = 127.5 + s*(i-127.5) + c*(j-127.5)
// Zeros padding folded into the bilinear weights; addresses clamped so all
// 16 loads per tap-group are unconditional and independent (ILP for latency).
__global__ __launch_bounds__(256) void radon_ray_kernel(const float* __restrict__ img,
                                                        float* __restrict__ out) {
    const int a = blockIdx.x;     // angle
    const int split = blockIdx.y; // i-chunk
    const int j = threadIdx.x;    // output position

    float ang = (float)a * (float)(M_PI / 179.0);
    float sn, cs;
    sincosf(ang, &sn, &cs);

    float ry = (float)j - 127.5f;
    float bx = fmaf(-sn, ry, 127.5f);
    float by = fmaf(cs, ry, 127.5f);

    const float* __restrict__ im0 = img;
    const float* __restrict__ im1 = img + S * S;
    const float* __restrict__ im2 = img + 2 * S * S;
    const float* __restrict__ im3 = img + 3 * S * S;

    float acc0 = 0.0f, acc1 = 0.0f, acc2 = 0.0f, acc3 = 0.0f;
    const int i0 = split * ISTEPS;

#pragma unroll 4
    for (int t = 0; t < ISTEPS; ++t) {
        int i = i0 + t;
        float rx = (float)i - 127.5f;
        float px = fmaf(cs, rx, bx);
        float py = fmaf(sn, rx, by);

        float x0f = floorf(px);
        float y0f = floorf(py);
        float wx = px - x0f;
        float wy = py - y0f;
        int x0 = (int)x0f;
        int y0 = (int)y0f;
        int x1 = x0 + 1;
        int y1 = y0 + 1;

        bool vx0 = ((unsigned)x0 < S);
        bool vx1 = ((unsigned)x1 < S);
        bool vy0 = ((unsigned)y0 < S);
        bool vy1 = ((unsigned)y1 < S);

        float ux = 1.0f - wx;
        float uy = 1.0f - wy;
        float w00 = (vx0 & vy0) ? ux * uy : 0.0f;
        float w10 = (vx1 & vy0) ? wx * uy : 0.0f;
        float w01 = (vx0 & vy1) ? ux * wy : 0.0f;
        float w11 = (vx1 & vy1) ? wx * wy : 0.0f;

        int xc0 = min(max(x0, 0), S - 1);
        int xc1 = min(max(x1, 0), S - 1);
        int yc0 = min(max(y0, 0), S - 1);
        int yc1 = min(max(y1, 0), S - 1);

        int r0 = yc0 << 8;
        int r1 = yc1 << 8;
        int a00 = r0 + xc0;
        int a10 = r0 + xc1;
        int a01 = r1 + xc0;
        int a11 = r1 + xc1;

        // 16 independent loads (4 corners x 4 batches)
        float b0v00 = im0[a00], b0v10 = im0[a10], b0v01 = im0[a01], b0v11 = im0[a11];
        float b1v00 = im1[a00], b1v10 = im1[a10], b1v01 = im1[a01], b1v11 = im1[a11];
        float b2v00 = im2[a00], b2v10 = im2[a10], b2v01 = im2[a01], b2v11 = im2[a11];
        float b3v00 = im3[a00], b3v10 = im3[a10], b3v01 = im3[a01], b3v11 = im3[a11];

        acc0 = fmaf(w00, b0v00, fmaf(w10, b0v10, fmaf(w01, b0v01, fmaf(w11, b0v11, acc0))));
        acc1 = fmaf(w00, b1v00, fmaf(w10, b1v10, fmaf(w01, b1v01, fmaf(w11, b1v11, acc1))));
        acc2 = fmaf(w00, b2v00, fmaf(w10, b2v10, fmaf(w01, b2v01, fmaf(w11, b2v11, acc2))));
        acc3 = fmaf(w00, b3v00, fmaf(w10, b3v10, fmaf(w01, b3v01, fmaf(w11, b3v11, acc3))));
    }

    atomicAdd(&out[(0 * A + a) * S + j], acc0);
    atomicAdd(&out[(1 * A + a) * S + j], acc1);
    atomicAdd(&out[(2 * A + a) * S + j], acc2);
    atomicAdd(&out[(3 * A + a) * S + j], acc3);
}

extern "C" void kernel_launch(void* const* d_in, const int* in_sizes, int n_in,
                              void* d_out, int out_size, void* d_ws, size_t ws_size,
                              hipStream_t stream) {
    const float* x = (const float*)d_in[0];
    float* out = (float*)d_out;
    float* masked = (float*)d_ws;  // B*S*S floats = 1 MiB

    radon_zero_kernel<<<dim3((out_size + 255) / 256), dim3(256), 0, stream>>>(out, out_size);
    radon_mask_kernel<<<dim3((B * S * S) / 256), dim3(256), 0, stream>>>(x, masked);
    radon_ray_kernel<<<dim3(A, NSPLIT), dim3(256), 0, stream>>>(masked, out);
}

// Round 5
// 138.186 us; speedup vs baseline: 2.5499x; 2.5499x over previous
//
#include <hip/hip_runtime.h>
#include <hip/hip_fp16.h>
#include <math.h>

#define S 256
#define A 180
#define B 4
#define LSTRIDE 258                  // halves per LDS row (even -> dword-aligned rows)
#define LROWS 257                    // 256 rows + 1 zero pad row

// Kernel 1: inscribed-circle mask (dx^2+dy^2 <= 128^2 == sqrt<=128) + fp32->fp16.
__global__ void radon_mask_f16(const float* __restrict__ in, __half* __restrict__ out) {
    int idx = blockIdx.x * 256 + threadIdx.x;    // 0 .. B*S*S-1
    int p = idx & (S * S - 1);
    int y = p >> 8;
    int x = p & 255;
    int dx = x - 128, dy = y - 128;
    float v = in[idx];
    v = (dx * dx + dy * dy <= 16384) ? v : 0.0f;
    out[idx] = __float2half(v);
}

// Kernel 2: one block per (angle, batch). Stage fp16 image into LDS (stride 258),
// thread (j, iq) integrates ray j over i-quarter iq, trimmed to d <= 130.13
// (beyond: every in-bounds corner is > 128 from (128,128) -> circle-masked to 0,
// OOB corners carry zero weight -> tap exactly 0). Interior d <= 126.5 needs no
// bounds logic. Rim path clamps EACH corner index independently (x1 corner of
// px in [-1,0) is column 0, not clamped-base+1 -- the R3/R4 bug).
__global__ __launch_bounds__(1024, 1) void radon_lds_kernel(const __half* __restrict__ img,
                                                            float* __restrict__ out) {
    __shared__ __half lds[LROWS * LSTRIDE];      // 132612 B

    const int a = blockIdx.x;   // angle
    const int b = blockIdx.y;   // batch
    const int tid = threadIdx.x;

    // ---- stage image (65536 halves = 32768 dwords), coalesced ----
    const uint* __restrict__ src = (const uint*)(img + (size_t)b * (S * S));
    uint* l32 = (uint*)lds;
#pragma unroll
    for (int k = 0; k < 32; ++k) {
        int p = k * 1024 + tid;
        int y = p >> 7;            // 128 dwords per source row
        int xp = p & 127;
        l32[y * (LSTRIDE / 2) + xp] = src[p];
    }
    // zero pad cols 256/257 of rows 0..255 and all of pad row 256
    if (tid < 256) {
        l32[tid * (LSTRIDE / 2) + 128] = 0u;
    } else if (tid < 256 + LSTRIDE / 2) {
        l32[256 * (LSTRIDE / 2) + (tid - 256)] = 0u;
    }
    __syncthreads();

    const int j = tid & 255;
    const int iq = tid >> 8;

    float ang = (float)a * (float)(M_PI / 179.0);
    float sn, cs;
    sincosf(ang, &sn, &cs);

    const float ry = (float)j - 127.5f;
    const float bx = fmaf(-sn, ry, 127.5f);
    const float by = fmaf(cs, ry, 127.5f);
    const float ry2 = ry * ry;

    // disk trim: keep i with rx^2 + ry^2 <= 16934 (~130.13^2 > provable 130.122)
    float h = sqrtf(16934.0f - ry2);
    int ilo = (int)ceilf(127.5f - h);
    int ihi = (int)floorf(127.5f + h) + 1;
    ilo = max(ilo, iq * 64);
    ihi = min(ihi, iq * 64 + 64);
    ilo = max(ilo, 0);
    ihi = min(ihi, S);

    const float FAST2 = 126.5f * 126.5f;
    float acc = 0.0f;

    for (int i = ilo; i < ihi; ++i) {
        float rx = (float)i - 127.5f;
        float px = fmaf(cs, rx, bx);
        float py = fmaf(sn, rx, by);

        float x0f = floorf(px);
        float y0f = floorf(py);
        float wx = px - x0f;
        float wy = py - y0f;
        int x0 = (int)x0f;
        int y0 = (int)y0f;
        float ux = 1.0f - wx;
        float uy = 1.0f - wy;
        float w00 = ux * uy;
        float w10 = wx * uy;
        float w01 = ux * wy;
        float w11 = wx * wy;

        float v00, v10, v01, v11;
        float d2 = fmaf(rx, rx, ry2);
        if (d2 <= FAST2) {
            // interior: px,py in [1,254] -> all corners in-bounds
            const __half* p0 = &lds[y0 * LSTRIDE + x0];
            v00 = __half2float(p0[0]);
            v10 = __half2float(p0[1]);
            v01 = __half2float(p0[LSTRIDE]);
            v11 = __half2float(p0[LSTRIDE + 1]);
        } else {
            // rim: zero weights of OOB corners, clamp each index independently
            bool vx0 = ((unsigned)x0 < S);
            bool vx1 = ((unsigned)(x0 + 1) < S);
            bool vy0 = ((unsigned)y0 < S);
            bool vy1 = ((unsigned)(y0 + 1) < S);
            w00 = (vx0 & vy0) ? w00 : 0.0f;
            w10 = (vx1 & vy0) ? w10 : 0.0f;
            w01 = (vx0 & vy1) ? w01 : 0.0f;
            w11 = (vx1 & vy1) ? w11 : 0.0f;
            int x0r = min(max(x0, 0), S - 1);
            int x1r = min(max(x0 + 1, 0), S);      // col 256 = zeroed pad
            int y0r = min(max(y0, 0), S - 1);
            int y1r = min(max(y0 + 1, 0), S);      // row 256 = zeroed pad
            v00 = __half2float(lds[y0r * LSTRIDE + x0r]);
            v10 = __half2float(lds[y0r * LSTRIDE + x1r]);
            v01 = __half2float(lds[y1r * LSTRIDE + x0r]);
            v11 = __half2float(lds[y1r * LSTRIDE + x1r]);
        }

        acc = fmaf(w00, v00, fmaf(w10, v10, fmaf(w01, v01, fmaf(w11, v11, acc))));
    }

    // ---- reduce the 4 i-quarters per j (reuse LDS after barrier) ----
    __syncthreads();
    float* red = (float*)lds;
    red[tid] = acc;
    __syncthreads();
    if (iq == 0) {
        float r = red[j] + red[j + 256] + red[j + 512] + red[j + 768];
        out[((size_t)b * A + a) * S + j] = r;
    }
}

extern "C" void kernel_launch(void* const* d_in, const int* in_sizes, int n_in,
                              void* d_out, int out_size, void* d_ws, size_t ws_size,
                              hipStream_t stream) {
    const float* x = (const float*)d_in[0];
    float* out = (float*)d_out;
    __half* masked = (__half*)d_ws;  // B*S*S halves = 512 KiB

    radon_mask_f16<<<dim3((B * S * S) / 256), dim3(256), 0, stream>>>(x, masked);
    radon_lds_kernel<<<dim3(A, B), dim3(1024), 0, stream>>>(masked, out);
}